// Round 10
// baseline (1301.955 us; speedup 1.0000x reference)
//
#include <hip/hip_runtime.h>
#include <hip/hip_bf16.h>
#include <math.h>

#define IGNORE_INDEX (-100)

typedef __attribute__((ext_vector_type(4))) float f32x4;
typedef __attribute__((ext_vector_type(16))) float f32x16;
typedef __attribute__((ext_vector_type(4))) int i32x4;
typedef __attribute__((ext_vector_type(8))) int i32x8;

// Problem sizes (fixed by the reference)
static const int NTOK = 2 * 4096;   // 8192 tokens (GEMM M)
static const int DIM  = 2048;       // embed dim (GEMM K)
static const int VOC  = 32000;      // vocab (GEMM N)
static const int BM = 256, BN = 256;
static const int KS = 64;           // K per slot
static const int NPH = DIM / KS;    // 32 slots
static const int NVT = VOC / BN;    // 125 vocab tiles
static const int MT  = NTOK / BM;   // 32 m tiles
static const float WSCALE = 16.0f;  // W pre-scale (exact power of 2)
#define SCL1 0x7F7F7F7F             // e8m0 scale byte 0x7F = 2^0 = 1.0

// ---------------- helpers ----------------

__device__ inline void gload_lds16(const void* g, void* l) {
  __builtin_amdgcn_global_load_lds(
      (const __attribute__((address_space(1))) void*)g,
      (__attribute__((address_space(3))) void*)l,
      16, 0, 0);
}

// ---------------- kernel 1: fp32 -> fp8 e4m3 cast (with scale) ----------------

__global__ void cast_f32_fp8(const float* __restrict__ in,
                             unsigned char* __restrict__ out, long n8, float scale) {
  long i0 = (long)blockIdx.x * blockDim.x + threadIdx.x;
  long stride = (long)gridDim.x * blockDim.x;
  for (long i = i0; i < n8; i += stride) {
    const float4* p = (const float4*)(in + i * 8);
    float4 a = p[0], b = p[1];
    int lo = __builtin_amdgcn_cvt_pk_fp8_f32(a.x * scale, a.y * scale, 0, false);
    lo = __builtin_amdgcn_cvt_pk_fp8_f32(a.z * scale, a.w * scale, lo, true);
    int hi = __builtin_amdgcn_cvt_pk_fp8_f32(b.x * scale, b.y * scale, 0, false);
    hi = __builtin_amdgcn_cvt_pk_fp8_f32(b.z * scale, b.w * scale, hi, true);
    int2 o; o.x = lo; o.y = hi;
    *(int2*)(out + i * 8) = o;
  }
}

// ---------------- kernel 2: 256x256 MX-fp8 GEMM (32x32x64), reg-dbuf, 1 barrier/slot ----
// Layout identical to R7 (verified absmax 0.0): fragment-major lane-linear LDS ring-4,
// frag f (32 rows x 64 k-bytes, 2KB) at slot*16384 + f*2048, half h at +h*1024 + lane*16.
// Schedule: per body: vmcnt(4) -> barrier -> stage slot n+3 -> ds_read slot n+1
// (named-variable reg set NXT) -> MFMA slot n (reg set CUR) -> lgkmcnt(0).
// One barrier/slot; MFMA overlaps the LDS drain; trailing lgkmcnt(0) closes the
// ring-4 WAR window (reads of ring r drain >=2 barriers before any re-stage of r).
// Operands: NAMED i32x4 vars (sets q*/r*), assembled via PACK8 initializers at MFMA
// time — never address-taken (R8's *(i32x4*)&v pattern spilled the dbuf to scratch).

#define VM8  asm volatile("s_waitcnt vmcnt(8)" ::: "memory")
#define VM4  asm volatile("s_waitcnt vmcnt(4)" ::: "memory")
#define VM0  asm volatile("s_waitcnt vmcnt(0)" ::: "memory")
#define BARRIER asm volatile("s_barrier" ::: "memory")
#define LGKM0 asm volatile("s_waitcnt lgkmcnt(0)" ::: "memory")

#define MS(ACC, AV, BV) \
  ACC = __builtin_amdgcn_mfma_scale_f32_32x32x64_f8f6f4( \
      AV, BV, ACC, 0, 0, 0, SCL1, 0, SCL1)

#define PACK8(LO, HI) {LO[0], LO[1], LO[2], LO[3], HI[0], HI[1], HI[2], HI[3]}

#define STAGE(DST) do { \
  char* _dA = stA + (DST) * 16384; \
  char* _dB = stB + (DST) * 16384; \
  gload_lds16(aS0, _dA); \
  gload_lds16(aS1, _dA + 1024); \
  gload_lds16(bS0, _dB); \
  gload_lds16(bS1, _dB + 1024); \
  aS0 += KS; aS1 += KS; bS0 += KS; bS1 += KS; \
} while (0)

// read slot (RING) into register set A (q*) or B (r*) — names referenced directly
#define READ12_A(RING) do { \
  const char* _Ab = aRd + (RING) * 16384; \
  const char* _Bb = bRd + (RING) * 16384; \
  qa0l = *(const i32x4*)(_Ab);        qa0h = *(const i32x4*)(_Ab + 1024); \
  qa1l = *(const i32x4*)(_Ab + 2048); qa1h = *(const i32x4*)(_Ab + 3072); \
  qa2l = *(const i32x4*)(_Ab + 4096); qa2h = *(const i32x4*)(_Ab + 5120); \
  qa3l = *(const i32x4*)(_Ab + 6144); qa3h = *(const i32x4*)(_Ab + 7168); \
  qb0l = *(const i32x4*)(_Bb);        qb0h = *(const i32x4*)(_Bb + 1024); \
  qb1l = *(const i32x4*)(_Bb + 2048); qb1h = *(const i32x4*)(_Bb + 3072); \
} while (0)

#define READ12_B(RING) do { \
  const char* _Ab = aRd + (RING) * 16384; \
  const char* _Bb = bRd + (RING) * 16384; \
  ra0l = *(const i32x4*)(_Ab);        ra0h = *(const i32x4*)(_Ab + 1024); \
  ra1l = *(const i32x4*)(_Ab + 2048); ra1h = *(const i32x4*)(_Ab + 3072); \
  ra2l = *(const i32x4*)(_Ab + 4096); ra2h = *(const i32x4*)(_Ab + 5120); \
  ra3l = *(const i32x4*)(_Ab + 6144); ra3h = *(const i32x4*)(_Ab + 7168); \
  rb0l = *(const i32x4*)(_Bb);        rb0h = *(const i32x4*)(_Bb + 1024); \
  rb1l = *(const i32x4*)(_Bb + 2048); rb1h = *(const i32x4*)(_Bb + 3072); \
} while (0)

#define MFMA8_A do { \
  i32x8 _B0 = PACK8(qb0l, qb0h); \
  i32x8 _B1 = PACK8(qb1l, qb1h); \
  i32x8 _A0 = PACK8(qa0l, qa0h); \
  i32x8 _A1 = PACK8(qa1l, qa1h); \
  i32x8 _A2 = PACK8(qa2l, qa2h); \
  i32x8 _A3 = PACK8(qa3l, qa3h); \
  __builtin_amdgcn_s_setprio(1); \
  MS(acc[0][0], _A0, _B0); MS(acc[0][1], _A0, _B1); \
  MS(acc[1][0], _A1, _B0); MS(acc[1][1], _A1, _B1); \
  MS(acc[2][0], _A2, _B0); MS(acc[2][1], _A2, _B1); \
  MS(acc[3][0], _A3, _B0); MS(acc[3][1], _A3, _B1); \
  __builtin_amdgcn_s_setprio(0); \
} while (0)

#define MFMA8_B do { \
  i32x8 _B0 = PACK8(rb0l, rb0h); \
  i32x8 _B1 = PACK8(rb1l, rb1h); \
  i32x8 _A0 = PACK8(ra0l, ra0h); \
  i32x8 _A1 = PACK8(ra1l, ra1h); \
  i32x8 _A2 = PACK8(ra2l, ra2h); \
  i32x8 _A3 = PACK8(ra3l, ra3h); \
  __builtin_amdgcn_s_setprio(1); \
  MS(acc[0][0], _A0, _B0); MS(acc[0][1], _A0, _B1); \
  MS(acc[1][0], _A1, _B0); MS(acc[1][1], _A1, _B1); \
  MS(acc[2][0], _A2, _B0); MS(acc[2][1], _A2, _B1); \
  MS(acc[3][0], _A3, _B0); MS(acc[3][1], _A3, _B1); \
  __builtin_amdgcn_s_setprio(0); \
} while (0)

__launch_bounds__(512, 2)
__global__ void lce_gemm(const unsigned char* __restrict__ xq,
                         const unsigned char* __restrict__ wq,
                         float* __restrict__ pmax, float* __restrict__ psum) {
  extern __shared__ char smem[];
  char* smA = smem;
  char* smB = smem + 65536;

  // XCD-aware swizzle (nwg = 4000, divisible by 8), mt-minor
  const int nwg = NVT * MT;            // 4000
  const int cpx = nwg >> 3;            // 500
  const int bid = blockIdx.x;
  const int swz = (bid & 7) * cpx + (bid >> 3);
  const int vt = swz / MT;
  const int mt = swz % MT;
  const int m0 = mt * BM;
  const int v0 = vt * BN;

  const int tid = threadIdx.x;
  const int lane = tid & 63;
  const int w = tid >> 6;              // 0..7
  const int wr = w >> 2, wc = w & 3;   // 2 x 4 wave grid; wave tile 128x64
  const int lc = lane & 31;
  const int lh = lane >> 5;

  f32x16 acc[4][2];
#pragma unroll
  for (int i = 0; i < 4; ++i)
#pragma unroll
    for (int j = 0; j < 2; ++j)
#pragma unroll
      for (int r = 0; r < 16; ++r) acc[i][j][r] = 0.f;

  // ---- staging sources (per-lane global; wave w owns A frag w + B frag w) ----
  const unsigned char* aS0 = xq + (long)(m0 + w * 32 + lc) * DIM + lh * 32;
  const unsigned char* aS1 = aS0 + 16;
  const unsigned char* bS0 = wq + (long)(v0 + w * 32 + lc) * DIM + lh * 32;
  const unsigned char* bS1 = bS0 + 16;
  char* stA = smA + w * 2048;
  char* stB = smB + w * 2048;

  // ---- ds_read bases (lane-linear) ----
  const char* aRd = smA + wr * 4 * 2048 + lane * 16;
  const char* bRd = smB + wc * 2 * 2048 + lane * 16;

  // ---- operand register sets (double buffer; named, never address-taken) ----
  i32x4 qa0l, qa0h, qa1l, qa1h, qa2l, qa2h, qa3l, qa3h, qb0l, qb0h, qb1l, qb1h;
  i32x4 ra0l, ra0h, ra1l, ra1h, ra2l, ra2h, ra3l, ra3h, rb0l, rb0h, rb1l, rb1h;

  // ---- prologue: stage slots 0,1,2; read slot 0 -> set A ----
  STAGE(0); STAGE(1); STAGE(2);
  VM8;       // own slot-0 loads done
  BARRIER;   // all waves' slot-0 loads done
  READ12_A(0);

  // ---- main loop: bodies 0..27 (pairs), then peeled 28,29,30 + final ----
#pragma unroll 1
  for (int n = 0; n < 28; n += 2) {
    // body n (even): MFMA slot n (set A); read slot n+1 -> set B; stage slot n+3
    VM4; BARRIER;
    STAGE((n + 3) & 3);
    READ12_B((n + 1) & 3);
    MFMA8_A;
    LGKM0;
    // body n+1 (odd): MFMA slot n+1 (set B); read slot n+2 -> set A; stage slot n+4
    VM4; BARRIER;
    STAGE((n + 4) & 3);
    READ12_A((n + 2) & 3);
    MFMA8_B;
    LGKM0;
  }
  // body 28: MFMA slot 28 (A); read slot 29 -> B; stage slot 31 (ring 3)
  VM4; BARRIER;
  STAGE(3);
  READ12_B(1);
  MFMA8_A;
  LGKM0;
  // body 29: MFMA slot 29 (B); read slot 30 -> A
  VM4; BARRIER;
  READ12_A(2);
  MFMA8_B;
  LGKM0;
  // body 30: MFMA slot 30 (A); read slot 31 -> B
  VM0; BARRIER;
  READ12_B(3);
  MFMA8_A;
  LGKM0;
  // final: MFMA slot 31 (B)
  MFMA8_B;

  // ---- epilogue: per-row max & sum(exp) over this tile's 256 cols; logits = acc/WSCALE ----
  // 32x32 C/D layout (verified m74/m101): col = lane&31, row = (r&3) + 8*(r>>2) + 4*(lane>>5)
  const float sc = 1.0f / WSCALE;
  float* sm_m = (float*)smem;          // [4][256]
  float* sm_s = (float*)(smem + 4096); // [4][256]
  __syncthreads();                     // loop fully drained; safe to reuse LDS
#pragma unroll
  for (int i = 0; i < 4; ++i) {
#pragma unroll
    for (int r = 0; r < 16; ++r) {
      float l0 = acc[i][0][r] * sc, l1 = acc[i][1][r] * sc;
      float m = fmaxf(l0, l1);
#pragma unroll
      for (int mk = 1; mk < 32; mk <<= 1) m = fmaxf(m, __shfl_xor(m, mk));
      float s = __expf(l0 - m) + __expf(l1 - m);
#pragma unroll
      for (int mk = 1; mk < 32; mk <<= 1) s += __shfl_xor(s, mk);
      if (lc == 0) {
        int R = wr * 128 + i * 32 + (r & 3) + 8 * (r >> 2) + 4 * lh;
        sm_m[wc * 256 + R] = m;
        sm_s[wc * 256 + R] = s;
      }
    }
  }
  __syncthreads();
  if (tid < BM) {
    float ma = sm_m[tid], mb = sm_m[256 + tid], mc = sm_m[512 + tid], md = sm_m[768 + tid];
    float gm = fmaxf(fmaxf(ma, mb), fmaxf(mc, md));
    float gs = sm_s[tid] * __expf(ma - gm) + sm_s[256 + tid] * __expf(mb - gm) +
               sm_s[512 + tid] * __expf(mc - gm) + sm_s[768 + tid] * __expf(md - gm);
    long row = (long)(m0 + tid);
    pmax[row * NVT + vt] = gm;
    psum[row * NVT + vt] = gs;
  }
}

// ---------------- kernel 3: per-token LSE combine + exact fp32 target dot ----------------

__global__ void token_reduce(const float* __restrict__ x, const float* __restrict__ wgt,
                             const int* __restrict__ tgt,
                             const float* __restrict__ pmax, const float* __restrict__ psum,
                             float* __restrict__ nll, float* __restrict__ validf) {
  const int n = blockIdx.x;
  const int tid = threadIdx.x;
  const int lane = tid & 63;
  const int w = tid >> 6;
  __shared__ float smr[4];

  const int t = tgt[n];
  const bool valid = (t != IGNORE_INDEX);
  const int ts = valid ? t : 0;

  // exact fp32 target logit
  const float4* xr = (const float4*)(x + (long)n * DIM);
  const float4* wr = (const float4*)(wgt + (long)ts * DIM);
  float d = 0.f;
  for (int i = tid; i < DIM / 4; i += blockDim.x) {
    float4 a = xr[i], b = wr[i];
    d += a.x * b.x + a.y * b.y + a.z * b.z + a.w * b.w;
  }

  // LSE over 125 partials
  float m = (tid < NVT) ? pmax[(long)n * NVT + tid] : -INFINITY;
  float t1 = m;
#pragma unroll
  for (int mk = 1; mk < 64; mk <<= 1) t1 = fmaxf(t1, __shfl_xor(t1, mk));
  if (lane == 0) smr[w] = t1;
  __syncthreads();
  const float gm = fmaxf(fmaxf(smr[0], smr[1]), fmaxf(smr[2], smr[3]));
  __syncthreads();

  float se = (tid < NVT) ? psum[(long)n * NVT + tid] * __expf(m - gm) : 0.f;
#pragma unroll
  for (int mk = 1; mk < 64; mk <<= 1) se += __shfl_xor(se, mk);
  if (lane == 0) smr[w] = se;
  __syncthreads();
  const float gs = smr[0] + smr[1] + smr[2] + smr[3];
  __syncthreads();

#pragma unroll
  for (int mk = 1; mk < 64; mk <<= 1) d += __shfl_xor(d, mk);
  if (lane == 0) smr[w] = d;
  __syncthreads();
  const float gd = smr[0] + smr[1] + smr[2] + smr[3];

  if (tid == 0) {
    nll[n] = valid ? (gm + logf(gs) - gd) : 0.f;
    validf[n] = valid ? 1.f : 0.f;
  }
}

// ---------------- kernel 4: deterministic final mean ----------------

__global__ void final_reduce(const float* __restrict__ nll, const float* __restrict__ validf,
                             float* __restrict__ out, int n) {
  const int tid = threadIdx.x;
  const int lane = tid & 63;
  const int w = tid >> 6;
  __shared__ float sm1[4], sm2[4];
  float s = 0.f, c = 0.f;
  for (int i = tid; i < n; i += blockDim.x) { s += nll[i]; c += validf[i]; }
#pragma unroll
  for (int mk = 1; mk < 64; mk <<= 1) { s += __shfl_xor(s, mk); c += __shfl_xor(c, mk); }
  if (lane == 0) { sm1[w] = s; sm2[w] = c; }
  __syncthreads();
  if (tid == 0) {
    float ts = sm1[0] + sm1[1] + sm1[2] + sm1[3];
    float tc = sm2[0] + sm2[1] + sm2[2] + sm2[3];
    out[0] = ts / fmaxf(tc, 1.0f);
  }
}

// ---------------- launch ----------------

extern "C" void kernel_launch(void* const* d_in, const int* in_sizes, int n_in,
                              void* d_out, int out_size, void* d_ws, size_t ws_size,
                              hipStream_t stream) {
  const float* x = (const float*)d_in[0];     // [8192, 2048] fp32
  const float* wgt = (const float*)d_in[1];   // [32000, 2048] fp32
  const int* tgt = (const int*)d_in[2];       // [8192] int
  float* out = (float*)d_out;

  char* ws = (char*)d_ws;
  const size_t xq_off = 0;
  const size_t wq_off = (size_t)NTOK * DIM;                        // 16,777,216
  const size_t pm_off = wq_off + (size_t)VOC * DIM;                // 82,313,216
  const size_t ps_off = pm_off + (size_t)NTOK * NVT * 4;
  const size_t nl_off = ps_off + (size_t)NTOK * NVT * 4;
  const size_t vf_off = nl_off + (size_t)NTOK * 4;
  const size_t needed = vf_off + (size_t)NTOK * 4;
  if (ws_size < needed) return;  // workspace too small: fail visibly

  unsigned char* xq = (unsigned char*)(ws + xq_off);
  unsigned char* wq = (unsigned char*)(ws + wq_off);
  float* pmax = (float*)(ws + pm_off);
  float* psum = (float*)(ws + ps_off);
  float* nllv = (float*)(ws + nl_off);
  float* vldf = (float*)(ws + vf_off);

  cast_f32_fp8<<<2048, 256, 0, stream>>>(x, xq, (long)NTOK * DIM / 8, 1.0f);
  cast_f32_fp8<<<4096, 256, 0, stream>>>(wgt, wq, (long)VOC * DIM / 8, WSCALE);

  (void)hipFuncSetAttribute((const void*)lce_gemm,
                            hipFuncAttributeMaxDynamicSharedMemorySize, 131072);
  lce_gemm<<<NVT * MT, 512, 131072, stream>>>(xq, wq, pmax, psum);

  token_reduce<<<NTOK, 256, 0, stream>>>(x, wgt, tgt, pmax, psum, nllv, vldf);
  final_reduce<<<1, 256, 0, stream>>>(nllv, vldf, out, NTOK);
}

// Round 11
// 1081.658 us; speedup vs baseline: 1.2037x; 1.2037x over previous
//
#include <hip/hip_runtime.h>
#include <hip/hip_bf16.h>
#include <math.h>

#define IGNORE_INDEX (-100)

typedef __attribute__((ext_vector_type(4))) float f32x4;
typedef __attribute__((ext_vector_type(16))) float f32x16;
typedef __attribute__((ext_vector_type(4))) int i32x4;
typedef __attribute__((ext_vector_type(8))) int i32x8;

// Problem sizes (fixed by the reference)
static const int NTOK = 2 * 4096;   // 8192 tokens (GEMM M)
static const int DIM  = 2048;       // embed dim (GEMM K)
static const int VOC  = 32000;      // vocab (GEMM N)
static const int BM = 256, BN = 256;
static const int KS = 64;           // K per slot
static const int NPH = DIM / KS;    // 32 slots
static const int NVT = VOC / BN;    // 125 vocab tiles
static const int MT  = NTOK / BM;   // 32 m tiles
static const float WSCALE = 16.0f;  // W pre-scale (exact power of 2)
#define SCL1 0x7F7F7F7F             // e8m0 scale byte 0x7F = 2^0 = 1.0

// ---------------- helpers ----------------

__device__ inline void gload_lds16(const void* g, void* l) {
  __builtin_amdgcn_global_load_lds(
      (const __attribute__((address_space(1))) void*)g,
      (__attribute__((address_space(3))) void*)l,
      16, 0, 0);
}

// ---------------- kernel 1: fp32 -> fp8 e4m3 cast (with scale) ----------------

__global__ void cast_f32_fp8(const float* __restrict__ in,
                             unsigned char* __restrict__ out, long n8, float scale) {
  long i0 = (long)blockIdx.x * blockDim.x + threadIdx.x;
  long stride = (long)gridDim.x * blockDim.x;
  for (long i = i0; i < n8; i += stride) {
    const float4* p = (const float4*)(in + i * 8);
    float4 a = p[0], b = p[1];
    int lo = __builtin_amdgcn_cvt_pk_fp8_f32(a.x * scale, a.y * scale, 0, false);
    lo = __builtin_amdgcn_cvt_pk_fp8_f32(a.z * scale, a.w * scale, lo, true);
    int hi = __builtin_amdgcn_cvt_pk_fp8_f32(b.x * scale, b.y * scale, 0, false);
    hi = __builtin_amdgcn_cvt_pk_fp8_f32(b.z * scale, b.w * scale, hi, true);
    int2 o; o.x = lo; o.y = hi;
    *(int2*)(out + i * 8) = o;
  }
}

// ---------------- kernel 2: 256x256 MX-fp8 GEMM (32x32x64), compiler-scheduled slot ----
// Layout identical to R7 (verified absmax 0.0): fragment-major lane-linear LDS ring-4,
// frag f (32 rows x 64 k-bytes, 2KB) at slot*16384 + f*2048, half h at +h*1024 + lane*16.
// R11 schedule: ONE barrier per slot, SINGLE operand set, NO explicit lgkmcnt —
//   VM8 -> barrier -> stage slot n+3 -> 12 plain ds_reads -> pack + 8 MFMA.
// The compiler inserts per-dependency lgkmcnt(N): the first MFMA fires when its own
// 4 operand reads land; the remaining 8 reads drain underneath the MFMA cluster.
// Ring WAR is safe: each body's MFMAs consume all 12 reads (in-order DS FIFO) before
// the wave reaches the next barrier, which orders them against the re-stage.
// Single operand set (48 VGPR) keeps total regs ~210 < 256 (R8/R10's dbuf spilled).

#define VM8  asm volatile("s_waitcnt vmcnt(8)" ::: "memory")
#define VM4  asm volatile("s_waitcnt vmcnt(4)" ::: "memory")
#define VM0  asm volatile("s_waitcnt vmcnt(0)" ::: "memory")
#define BARRIER asm volatile("s_barrier" ::: "memory")

#define MS(ACC, AV, BV) \
  ACC = __builtin_amdgcn_mfma_scale_f32_32x32x64_f8f6f4( \
      AV, BV, ACC, 0, 0, 0, SCL1, 0, SCL1)

#define PACK8(LO, HI) {LO[0], LO[1], LO[2], LO[3], HI[0], HI[1], HI[2], HI[3]}

#define STAGE(DST) do { \
  char* _dA = stA + (DST) * 16384; \
  char* _dB = stB + (DST) * 16384; \
  gload_lds16(aS0, _dA); \
  gload_lds16(aS1, _dA + 1024); \
  gload_lds16(bS0, _dB); \
  gload_lds16(bS1, _dB + 1024); \
  aS0 += KS; aS1 += KS; bS0 += KS; bS1 += KS; \
} while (0)

// read slot (RING) into the single named register set, then pack + 8 MFMA
#define SLOT_COMPUTE(RING) do { \
  const char* _Ab = aRd + (RING) * 16384; \
  const char* _Bb = bRd + (RING) * 16384; \
  i32x4 qb0l = *(const i32x4*)(_Bb);        i32x4 qb0h = *(const i32x4*)(_Bb + 1024); \
  i32x4 qa0l = *(const i32x4*)(_Ab);        i32x4 qa0h = *(const i32x4*)(_Ab + 1024); \
  i32x4 qb1l = *(const i32x4*)(_Bb + 2048); i32x4 qb1h = *(const i32x4*)(_Bb + 3072); \
  i32x4 qa1l = *(const i32x4*)(_Ab + 2048); i32x4 qa1h = *(const i32x4*)(_Ab + 3072); \
  i32x4 qa2l = *(const i32x4*)(_Ab + 4096); i32x4 qa2h = *(const i32x4*)(_Ab + 5120); \
  i32x4 qa3l = *(const i32x4*)(_Ab + 6144); i32x4 qa3h = *(const i32x4*)(_Ab + 7168); \
  i32x8 _B0 = PACK8(qb0l, qb0h); \
  i32x8 _A0 = PACK8(qa0l, qa0h); \
  i32x8 _B1 = PACK8(qb1l, qb1h); \
  i32x8 _A1 = PACK8(qa1l, qa1h); \
  __builtin_amdgcn_s_setprio(1); \
  MS(acc[0][0], _A0, _B0); MS(acc[0][1], _A0, _B1); \
  MS(acc[1][0], _A1, _B0); MS(acc[1][1], _A1, _B1); \
  { \
    i32x8 _A2 = PACK8(qa2l, qa2h); \
    i32x8 _A3 = PACK8(qa3l, qa3h); \
    MS(acc[2][0], _A2, _B0); MS(acc[2][1], _A2, _B1); \
    MS(acc[3][0], _A3, _B0); MS(acc[3][1], _A3, _B1); \
  } \
  __builtin_amdgcn_s_setprio(0); \
} while (0)

__launch_bounds__(512, 2)
__global__ void lce_gemm(const unsigned char* __restrict__ xq,
                         const unsigned char* __restrict__ wq,
                         float* __restrict__ pmax, float* __restrict__ psum) {
  extern __shared__ char smem[];
  char* smA = smem;
  char* smB = smem + 65536;

  // XCD-aware swizzle (nwg = 4000, divisible by 8), mt-minor
  const int nwg = NVT * MT;            // 4000
  const int cpx = nwg >> 3;            // 500
  const int bid = blockIdx.x;
  const int swz = (bid & 7) * cpx + (bid >> 3);
  const int vt = swz / MT;
  const int mt = swz % MT;
  const int m0 = mt * BM;
  const int v0 = vt * BN;

  const int tid = threadIdx.x;
  const int lane = tid & 63;
  const int w = tid >> 6;              // 0..7
  const int wr = w >> 2, wc = w & 3;   // 2 x 4 wave grid; wave tile 128x64
  const int lc = lane & 31;
  const int lh = lane >> 5;

  f32x16 acc[4][2];
#pragma unroll
  for (int i = 0; i < 4; ++i)
#pragma unroll
    for (int j = 0; j < 2; ++j)
#pragma unroll
      for (int r = 0; r < 16; ++r) acc[i][j][r] = 0.f;

  // ---- staging sources (per-lane global; wave w owns A frag w + B frag w) ----
  const unsigned char* aS0 = xq + (long)(m0 + w * 32 + lc) * DIM + lh * 32;
  const unsigned char* aS1 = aS0 + 16;
  const unsigned char* bS0 = wq + (long)(v0 + w * 32 + lc) * DIM + lh * 32;
  const unsigned char* bS1 = bS0 + 16;
  char* stA = smA + w * 2048;
  char* stB = smB + w * 2048;

  // ---- ds_read bases (lane-linear) ----
  const char* aRd = smA + wr * 4 * 2048 + lane * 16;
  const char* bRd = smB + wc * 2 * 2048 + lane * 16;

  // ---- prologue: stage slots 0,1,2 ----
  STAGE(0); STAGE(1); STAGE(2);

  // ---- main loop: one barrier per slot; compiler-scheduled reads/MFMA overlap ----
#pragma unroll 1
  for (int n = 0; n < NPH; ++n) {
    // wait for slot n's 4 staged loads (per-wave), then publish via barrier
    if (n <= NPH - 3) { VM8; }
    else if (n == NPH - 2) { VM4; }
    else { VM0; }
    BARRIER;
    if (n < NPH - 3) STAGE((n + 3) & 3);
    SLOT_COMPUTE(n & 3);
  }

  // ---- epilogue: per-row max & sum(exp) over this tile's 256 cols; logits = acc/WSCALE ----
  // 32x32 C/D layout (verified m74/m101): col = lane&31, row = (r&3) + 8*(r>>2) + 4*(lane>>5)
  const float sc = 1.0f / WSCALE;
  float* sm_m = (float*)smem;          // [4][256]
  float* sm_s = (float*)(smem + 4096); // [4][256]
  __syncthreads();                     // loop fully drained; safe to reuse LDS
#pragma unroll
  for (int i = 0; i < 4; ++i) {
#pragma unroll
    for (int r = 0; r < 16; ++r) {
      float l0 = acc[i][0][r] * sc, l1 = acc[i][1][r] * sc;
      float m = fmaxf(l0, l1);
#pragma unroll
      for (int mk = 1; mk < 32; mk <<= 1) m = fmaxf(m, __shfl_xor(m, mk));
      float s = __expf(l0 - m) + __expf(l1 - m);
#pragma unroll
      for (int mk = 1; mk < 32; mk <<= 1) s += __shfl_xor(s, mk);
      if (lc == 0) {
        int R = wr * 128 + i * 32 + (r & 3) + 8 * (r >> 2) + 4 * lh;
        sm_m[wc * 256 + R] = m;
        sm_s[wc * 256 + R] = s;
      }
    }
  }
  __syncthreads();
  if (tid < BM) {
    float ma = sm_m[tid], mb = sm_m[256 + tid], mc = sm_m[512 + tid], md = sm_m[768 + tid];
    float gm = fmaxf(fmaxf(ma, mb), fmaxf(mc, md));
    float gs = sm_s[tid] * __expf(ma - gm) + sm_s[256 + tid] * __expf(mb - gm) +
               sm_s[512 + tid] * __expf(mc - gm) + sm_s[768 + tid] * __expf(md - gm);
    long row = (long)(m0 + tid);
    pmax[row * NVT + vt] = gm;
    psum[row * NVT + vt] = gs;
  }
}

// ---------------- kernel 3: per-token LSE combine + exact fp32 target dot ----------------

__global__ void token_reduce(const float* __restrict__ x, const float* __restrict__ wgt,
                             const int* __restrict__ tgt,
                             const float* __restrict__ pmax, const float* __restrict__ psum,
                             float* __restrict__ nll, float* __restrict__ validf) {
  const int n = blockIdx.x;
  const int tid = threadIdx.x;
  const int lane = tid & 63;
  const int w = tid >> 6;
  __shared__ float smr[4];

  const int t = tgt[n];
  const bool valid = (t != IGNORE_INDEX);
  const int ts = valid ? t : 0;

  // exact fp32 target logit
  const float4* xr = (const float4*)(x + (long)n * DIM);
  const float4* wr = (const float4*)(wgt + (long)ts * DIM);
  float d = 0.f;
  for (int i = tid; i < DIM / 4; i += blockDim.x) {
    float4 a = xr[i], b = wr[i];
    d += a.x * b.x + a.y * b.y + a.z * b.z + a.w * b.w;
  }

  // LSE over 125 partials
  float m = (tid < NVT) ? pmax[(long)n * NVT + tid] : -INFINITY;
  float t1 = m;
#pragma unroll
  for (int mk = 1; mk < 64; mk <<= 1) t1 = fmaxf(t1, __shfl_xor(t1, mk));
  if (lane == 0) smr[w] = t1;
  __syncthreads();
  const float gm = fmaxf(fmaxf(smr[0], smr[1]), fmaxf(smr[2], smr[3]));
  __syncthreads();

  float se = (tid < NVT) ? psum[(long)n * NVT + tid] * __expf(m - gm) : 0.f;
#pragma unroll
  for (int mk = 1; mk < 64; mk <<= 1) se += __shfl_xor(se, mk);
  if (lane == 0) smr[w] = se;
  __syncthreads();
  const float gs = smr[0] + smr[1] + smr[2] + smr[3];
  __syncthreads();

#pragma unroll
  for (int mk = 1; mk < 64; mk <<= 1) d += __shfl_xor(d, mk);
  if (lane == 0) smr[w] = d;
  __syncthreads();
  const float gd = smr[0] + smr[1] + smr[2] + smr[3];

  if (tid == 0) {
    nll[n] = valid ? (gm + logf(gs) - gd) : 0.f;
    validf[n] = valid ? 1.f : 0.f;
  }
}

// ---------------- kernel 4: deterministic final mean ----------------

__global__ void final_reduce(const float* __restrict__ nll, const float* __restrict__ validf,
                             float* __restrict__ out, int n) {
  const int tid = threadIdx.x;
  const int lane = tid & 63;
  const int w = tid >> 6;
  __shared__ float sm1[4], sm2[4];
  float s = 0.f, c = 0.f;
  for (int i = tid; i < n; i += blockDim.x) { s += nll[i]; c += validf[i]; }
#pragma unroll
  for (int mk = 1; mk < 64; mk <<= 1) { s += __shfl_xor(s, mk); c += __shfl_xor(c, mk); }
  if (lane == 0) { sm1[w] = s; sm2[w] = c; }
  __syncthreads();
  if (tid == 0) {
    float ts = sm1[0] + sm1[1] + sm1[2] + sm1[3];
    float tc = sm2[0] + sm2[1] + sm2[2] + sm2[3];
    out[0] = ts / fmaxf(tc, 1.0f);
  }
}

// ---------------- launch ----------------

extern "C" void kernel_launch(void* const* d_in, const int* in_sizes, int n_in,
                              void* d_out, int out_size, void* d_ws, size_t ws_size,
                              hipStream_t stream) {
  const float* x = (const float*)d_in[0];     // [8192, 2048] fp32
  const float* wgt = (const float*)d_in[1];   // [32000, 2048] fp32
  const int* tgt = (const int*)d_in[2];       // [8192] int
  float* out = (float*)d_out;

  char* ws = (char*)d_ws;
  const size_t xq_off = 0;
  const size_t wq_off = (size_t)NTOK * DIM;                        // 16,777,216
  const size_t pm_off = wq_off + (size_t)VOC * DIM;                // 82,313,216
  const size_t ps_off = pm_off + (size_t)NTOK * NVT * 4;
  const size_t nl_off = ps_off + (size_t)NTOK * NVT * 4;
  const size_t vf_off = nl_off + (size_t)NTOK * 4;
  const size_t needed = vf_off + (size_t)NTOK * 4;
  if (ws_size < needed) return;  // workspace too small: fail visibly

  unsigned char* xq = (unsigned char*)(ws + xq_off);
  unsigned char* wq = (unsigned char*)(ws + wq_off);
  float* pmax = (float*)(ws + pm_off);
  float* psum = (float*)(ws + ps_off);
  float* nllv = (float*)(ws + nl_off);
  float* vldf = (float*)(ws + vf_off);

  cast_f32_fp8<<<2048, 256, 0, stream>>>(x, xq, (long)NTOK * DIM / 8, 1.0f);
  cast_f32_fp8<<<4096, 256, 0, stream>>>(wgt, wq, (long)VOC * DIM / 8, WSCALE);

  (void)hipFuncSetAttribute((const void*)lce_gemm,
                            hipFuncAttributeMaxDynamicSharedMemorySize, 131072);
  lce_gemm<<<NVT * MT, 512, 131072, stream>>>(xq, wq, pmax, psum);

  token_reduce<<<NTOK, 256, 0, stream>>>(x, wgt, tgt, pmax, psum, nllv, vldf);
  final_reduce<<<1, 256, 0, stream>>>(nllv, vldf, out, NTOK);
}